// Round 2
// baseline (1969.359 us; speedup 1.0000x reference)
//
#include <hip/hip_runtime.h>
#include <hip/hip_bf16.h>
#include <stdint.h>

#define U_CNT 200000
#define I_CNT 100000
#define N_CNT 300000
#define E_CNT 1000000
#define ATTR_D 8
#define H_DIM 32
#define NB_SCAN ((N_CNT + 255) / 256)

typedef __hip_bfloat16 bf16;

__device__ __forceinline__ float b2f(bf16 v) { return __bfloat162float(v); }

// dtype-flexible load/store: bf=1 -> bf16, bf=0 -> float32
__device__ __forceinline__ float ldf(const void* p, int i, int bf) {
    return bf ? b2f(((const bf16*)p)[i]) : ((const float*)p)[i];
}
__device__ __forceinline__ void stf(void* p, int i, int bf, float v) {
    if (bf) ((bf16*)p)[i] = __float2bfloat16(v);
    else    ((float*)p)[i] = v;
}

// ---------------- dtype detection from raw bits of user_w ----------------
// bf16 data: all u16s decode to sane bf16, ~none exactly zero.
// fp32 data: even-index u16s (low mantissa halves) are ~uniform garbage.
// bf16-rounded-stored-fp32: even-index u16s are exactly 0x0000/0x8000.
__global__ void k_detect(const unsigned short* __restrict__ u, int* __restrict__ flag) {
    __shared__ int sbad, szero;
    if (threadIdx.x == 0) { sbad = 0; szero = 0; }
    __syncthreads();
    int bad = 0, zero = 0;
    for (int i = threadIdx.x; i < 4096; i += 256) {
        unsigned short h = u[i];
        int ex = (h >> 7) & 0xFF;
        if ((h & 0x7FFF) == 0) zero++;
        else if (ex < 100 || ex > 140) bad++;
    }
    atomicAdd(&sbad, bad);
    atomicAdd(&szero, zero);
    __syncthreads();
    if (threadIdx.x == 0) {
        // fp32 if lots of garbage halves OR lots of exactly-zero halves
        *flag = (sbad > 512 || szero > 512) ? 0 : 1;
    }
}

// ---------------- init: deg = 1.0 (self loop), cnt = 0 ----------------
__global__ void k_init(float* __restrict__ deg, int* __restrict__ cnt) {
    int i = blockIdx.x * 256 + threadIdx.x;
    if (i < N_CNT) { deg[i] = 1.0f; cnt[i] = 0; }
}

// ---------------- edge MLP + degree/count accumulation ----------------
__global__ void k_edge_mlp(const int* __restrict__ src, const int* __restrict__ dst,
                           const void* __restrict__ attr,
                           const void* __restrict__ W1, const void* __restrict__ b1,
                           const void* __restrict__ W2, const void* __restrict__ b2,
                           float* __restrict__ wbuf, float* __restrict__ deg,
                           int* __restrict__ cnt, const int* __restrict__ flag) {
    __shared__ float sW1[ATTR_D * H_DIM];
    __shared__ float sb1[H_DIM];
    __shared__ float sW2[H_DIM];
    __shared__ float sb2;
    const int bf = *flag;
    int t = threadIdx.x;
    sW1[t] = ldf(W1, t, bf);
    if (t < H_DIM) { sb1[t] = ldf(b1, t, bf); sW2[t] = ldf(W2, t, bf); }
    if (t == 0) sb2 = ldf(b2, 0, bf);
    __syncthreads();
    int e = blockIdx.x * 256 + t;
    if (e >= E_CNT) return;
    float a[8];
    #pragma unroll
    for (int k = 0; k < 8; ++k) a[k] = ldf(attr, e * 8 + k, bf);
    float z = sb2;
    #pragma unroll
    for (int h = 0; h < H_DIM; ++h) {
        float acc = sb1[h];
        #pragma unroll
        for (int k = 0; k < 8; ++k) acc = fmaf(a[k], sW1[k * H_DIM + h], acc);
        acc = fmaxf(acc, 0.0f);
        z = fmaf(acc, sW2[h], z);
    }
    float w = 1.0f / (1.0f + __expf(-z));
    w = fmaxf(w, 1e-6f);
    wbuf[e] = w;
    int s = src[e], d = U_CNT + dst[e];
    atomicAdd(&deg[s], w);
    atomicAdd(&deg[d], w);
    atomicAdd(&cnt[s], 1);
    atomicAdd(&cnt[d], 1);
}

// ---------------- exclusive scan of cnt -> offs (3 kernels) ----------------
__global__ void k_scan1(const int* __restrict__ cnt, int* __restrict__ incl,
                        int* __restrict__ bsums) {
    __shared__ int s[256];
    int t = threadIdx.x;
    int i = blockIdx.x * 256 + t;
    int v = (i < N_CNT) ? cnt[i] : 0;
    s[t] = v;
    __syncthreads();
    #pragma unroll
    for (int off = 1; off < 256; off <<= 1) {
        int x = (t >= off) ? s[t - off] : 0;
        __syncthreads();
        s[t] += x;
        __syncthreads();
    }
    if (i < N_CNT) incl[i] = s[t];
    if (t == 255) bsums[blockIdx.x] = s[255];
}

__global__ void k_scan2(const int* __restrict__ bsums, int* __restrict__ bbase, int nb) {
    __shared__ int s[256];
    __shared__ int carry_s;
    int t = threadIdx.x;
    if (t == 0) carry_s = 0;
    __syncthreads();
    for (int start = 0; start < nb; start += 256) {
        int i = start + t;
        int v = (i < nb) ? bsums[i] : 0;
        s[t] = v;
        __syncthreads();
        #pragma unroll
        for (int off = 1; off < 256; off <<= 1) {
            int x = (t >= off) ? s[t - off] : 0;
            __syncthreads();
            s[t] += x;
            __syncthreads();
        }
        int carry = carry_s;
        if (i < nb) bbase[i] = carry + s[t] - v;  // exclusive
        __syncthreads();
        if (t == 255) carry_s += s[255];
        __syncthreads();
    }
}

__global__ void k_scan3(const int* __restrict__ incl, const int* __restrict__ cnt,
                        const int* __restrict__ bbase, const float* __restrict__ deg,
                        int* __restrict__ offs, int* __restrict__ cursor,
                        float* __restrict__ dis) {
    int i = blockIdx.x * 256 + threadIdx.x;
    if (i < N_CNT) {
        int v = bbase[blockIdx.x] + incl[i] - cnt[i];
        offs[i] = v;
        cursor[i] = v;
        dis[i] = rsqrtf(deg[i]);   // deg >= 1 always (self loop)
    }
    if (i == 0) offs[N_CNT] = 2 * E_CNT;
}

// ---------------- scatter edges into CSR (both directions) ----------------
__global__ void k_scatter(const int* __restrict__ src, const int* __restrict__ dst,
                          const float* __restrict__ wbuf, const float* __restrict__ dis,
                          int* __restrict__ cursor, int2* __restrict__ csr) {
    int e = blockIdx.x * 256 + threadIdx.x;
    if (e >= E_CNT) return;
    float w = wbuf[e];
    int s = src[e], d = U_CNT + dst[e];
    float dsrc = dis[s], ddst = dis[d];
    int pA = atomicAdd(&cursor[d], 1);
    csr[pA] = make_int2(s, __float_as_int(dsrc * w));   // col=d, row=s
    int pB = atomicAdd(&cursor[s], 1);
    csr[pB] = make_int2(d, __float_as_int(ddst * w));   // col=s, row=d
}

// ---------------- initial features: users (l2norm) ----------------
__global__ void k_users(const void* __restrict__ user_w, void* __restrict__ x0,
                        float* __restrict__ acc, const int* __restrict__ flag) {
    const int bf = *flag;
    int lane = threadIdx.x & 63;
    int wv = (blockIdx.x * blockDim.x + threadIdx.x) >> 6;
    int nw = (gridDim.x * blockDim.x) >> 6;
    for (int r = wv; r < U_CNT; r += nw) {
        int idx = r * 64 + lane;
        float v = ldf(user_w, idx, bf);
        float ss = v * v;
        #pragma unroll
        for (int m = 32; m >= 1; m >>= 1) ss += __shfl_xor(ss, m, 64);
        float n = sqrtf(ss);
        float o = v / fmaxf(n, 1e-12f);
        stf(x0, idx, bf, o);
        acc[idx] = o;
    }
}

// ---------------- initial features: items (meta + projection + l2norm) ----------------
__global__ void k_items(const void* __restrict__ audio, const void* __restrict__ art,
                        const void* __restrict__ alb, const int* __restrict__ aid,
                        const int* __restrict__ alid, const void* __restrict__ Wp,
                        const void* __restrict__ bp, void* __restrict__ x0,
                        float* __restrict__ acc, const int* __restrict__ flag) {
    const int bf = *flag;
    int lane = threadIdx.x & 63;
    // lane d holds column d of Wp [128 x 64] in registers
    float wreg[128];
    if (bf) {
        const bf16* W = (const bf16*)Wp;
        #pragma unroll
        for (int k = 0; k < 128; ++k) wreg[k] = b2f(W[k * 64 + lane]);
    } else {
        const float* W = (const float*)Wp;
        #pragma unroll
        for (int k = 0; k < 128; ++k) wreg[k] = W[k * 64 + lane];
    }
    float bias = ldf(bp, lane, bf);
    int wv = (blockIdx.x * blockDim.x + threadIdx.x) >> 6;
    int nw = (gridDim.x * blockDim.x) >> 6;
    for (int i = wv; i < I_CNT; i += nw) {
        float vlow = ldf(audio, i * 64 + lane, bf);   // AUDIO_SCALE=1
        int a_ = aid[i], al_ = alid[i];
        float vhigh = ldf(art, a_ * 64 + lane, bf) + ldf(alb, al_ * 64 + lane, bf);
        float a0 = bias, a1 = 0.f, a2 = 0.f, a3 = 0.f;
        #pragma unroll
        for (int k = 0; k < 64; k += 4) {
            a0 = fmaf(__shfl(vlow, k + 0, 64), wreg[k + 0], a0);
            a1 = fmaf(__shfl(vlow, k + 1, 64), wreg[k + 1], a1);
            a2 = fmaf(__shfl(vlow, k + 2, 64), wreg[k + 2], a2);
            a3 = fmaf(__shfl(vlow, k + 3, 64), wreg[k + 3], a3);
        }
        #pragma unroll
        for (int k = 0; k < 64; k += 4) {
            a0 = fmaf(__shfl(vhigh, k + 0, 64), wreg[64 + k + 0], a0);
            a1 = fmaf(__shfl(vhigh, k + 1, 64), wreg[64 + k + 1], a1);
            a2 = fmaf(__shfl(vhigh, k + 2, 64), wreg[64 + k + 2], a2);
            a3 = fmaf(__shfl(vhigh, k + 3, 64), wreg[64 + k + 3], a3);
        }
        float o = (a0 + a1) + (a2 + a3);
        float ss = o * o;
        #pragma unroll
        for (int m = 32; m >= 1; m >>= 1) ss += __shfl_xor(ss, m, 64);
        float n = sqrtf(ss);
        o = o / fmaxf(n, 1e-12f);
        int idx = (U_CNT + i) * 64 + lane;
        stf(x0, idx, bf, o);
        acc[idx] = o;
    }
}

// ---------------- one LGConv propagation round (gather CSR) ----------------
__global__ void k_prop(const int* __restrict__ offs, const int2* __restrict__ csr,
                       const float* __restrict__ dis,
                       const void* __restrict__ xin, void* __restrict__ xout,
                       float* __restrict__ acc, const int* __restrict__ flag) {
    const int bf = *flag;
    int lane = threadIdx.x & 63;
    int c = (blockIdx.x * 256 + threadIdx.x) >> 6;   // wave per node
    if (c >= N_CNT) return;
    int e = offs[c], end = offs[c + 1];
    float dc = dis[c];
    float sum = 0.0f;
    for (; e + 1 < end; e += 2) {
        int2 e0 = csr[e];
        int2 e1 = csr[e + 1];
        float x0v = ldf(xin, e0.x * 64 + lane, bf);
        float x1v = ldf(xin, e1.x * 64 + lane, bf);
        sum = fmaf(__int_as_float(e0.y), x0v, sum);
        sum = fmaf(__int_as_float(e1.y), x1v, sum);
    }
    if (e < end) {
        int2 e0 = csr[e];
        sum = fmaf(__int_as_float(e0.y), ldf(xin, e0.x * 64 + lane, bf), sum);
    }
    int idx = c * 64 + lane;
    float selfv = ldf(xin, idx, bf);
    float res = fmaf(dc, sum, selfv * dc * dc);     // self loop: dis^2 * x
    stf(xout, idx, bf, res);
    acc[idx] += res;
}

// ---------------- epilogue: l2norm(acc/4) -> out (dtype per flag) ----------------
__global__ void k_final(const float* __restrict__ acc, void* __restrict__ out,
                        const int* __restrict__ flag) {
    const int bf = *flag;
    int lane = threadIdx.x & 63;
    int c = (blockIdx.x * 256 + threadIdx.x) >> 6;
    if (c >= N_CNT) return;
    float v = acc[c * 64 + lane];
    float ss = v * v;
    #pragma unroll
    for (int m = 32; m >= 1; m >>= 1) ss += __shfl_xor(ss, m, 64);
    float n = sqrtf(ss) * 0.25f;
    float a = v * 0.25f;
    stf(out, c * 64 + lane, bf, a / fmaxf(n, 1e-12f));
}

extern "C" void kernel_launch(void* const* d_in, const int* in_sizes, int n_in,
                              void* d_out, int out_size, void* d_ws, size_t ws_size,
                              hipStream_t stream) {
    const int*  edge_src   = (const int*) d_in[0];
    const int*  edge_dst   = (const int*) d_in[1];
    const void* edge_attr  = d_in[2];
    const void* user_w     = d_in[3];
    const void* artist_w   = d_in[4];
    const void* album_w    = d_in[5];
    const void* item_audio = d_in[6];
    const int*  artist_ids = (const int*) d_in[7];
    const int*  album_ids  = (const int*) d_in[8];
    const void* Wp         = d_in[9];
    const void* bp         = d_in[10];
    const void* W1         = d_in[11];
    const void* b1         = d_in[12];
    const void* W2         = d_in[13];
    const void* b2         = d_in[14];

    // workspace carve (256B-aligned): ~180 MB worst case (fp32 internal)
    char* p = (char*)d_ws;
    auto carve = [&](size_t bytes) -> void* {
        void* q = (void*)p;
        p += (bytes + 255) & ~(size_t)255;
        return q;
    };
    int*   flag   = (int*)  carve(4);
    float* deg    = (float*)carve((size_t)N_CNT * 4);
    float* dis    = (float*)carve((size_t)N_CNT * 4);
    float* wbuf   = (float*)carve((size_t)E_CNT * 4);
    int*   cnt    = (int*)  carve((size_t)N_CNT * 4);
    int*   offs   = (int*)  carve((size_t)(N_CNT + 1) * 4);
    int*   cursor = (int*)  carve((size_t)N_CNT * 4);
    int*   incl   = (int*)  carve((size_t)N_CNT * 4);
    int*   bsums  = (int*)  carve((size_t)NB_SCAN * 4);
    int*   bbase  = (int*)  carve((size_t)NB_SCAN * 4);
    int2*  csr    = (int2*) carve((size_t)2 * E_CNT * 8);
    void*  xa     = (void*) carve((size_t)N_CNT * 64 * 4);   // fp32-capable
    float* acc    = (float*)carve((size_t)N_CNT * 64 * 4);
    void*  xb     = d_out;   // d_out doubles as ping-pong buffer (same dtype/size)
    (void)ws_size; (void)in_sizes; (void)n_in; (void)out_size;

    k_detect <<<1, 256, 0, stream>>>((const unsigned short*)user_w, flag);
    k_init   <<<(N_CNT + 255) / 256, 256, 0, stream>>>(deg, cnt);
    k_edge_mlp<<<(E_CNT + 255) / 256, 256, 0, stream>>>(edge_src, edge_dst, edge_attr,
                                                        W1, b1, W2, b2, wbuf, deg, cnt, flag);
    k_scan1  <<<NB_SCAN, 256, 0, stream>>>(cnt, incl, bsums);
    k_scan2  <<<1, 256, 0, stream>>>(bsums, bbase, NB_SCAN);
    k_scan3  <<<NB_SCAN, 256, 0, stream>>>(incl, cnt, bbase, deg, offs, cursor, dis);
    k_scatter<<<(E_CNT + 255) / 256, 256, 0, stream>>>(edge_src, edge_dst, wbuf, dis,
                                                       cursor, csr);
    k_users  <<<1024, 256, 0, stream>>>(user_w, xa, acc, flag);
    k_items  <<<1024, 256, 0, stream>>>(item_audio, artist_w, album_w, artist_ids,
                                        album_ids, Wp, bp, xa, acc, flag);
    // 3 LGConv rounds: xa -> xb(d_out) -> xa -> xb, accumulate into acc
    k_prop   <<<N_CNT / 4, 256, 0, stream>>>(offs, csr, dis, xa, xb, acc, flag);
    k_prop   <<<N_CNT / 4, 256, 0, stream>>>(offs, csr, dis, xb, xa, acc, flag);
    k_prop   <<<N_CNT / 4, 256, 0, stream>>>(offs, csr, dis, xa, xb, acc, flag);
    k_final  <<<N_CNT / 4, 256, 0, stream>>>(acc, d_out, flag);
}

// Round 5
// 1151.748 us; speedup vs baseline: 1.7099x; 1.7099x over previous
//
#include <hip/hip_runtime.h>
#include <hip/hip_bf16.h>

#define U_CNT 200000
#define I_CNT 100000
#define N_CNT 300000
#define E_CNT 1000000
#define ATTR_D 8
#define H_DIM 32
#define NB_SCAN ((N_CNT + 255) / 256)

// NOTE (round 1-4 post-mortem): all float inputs and the output are FLOAT32.
// Hard-coded bf16 variants NaN'd (fp32 bits decoded as bf16 garbage); the
// runtime-detector build that passed in round 2 was running its fp32 path.

// ---------------- init: deg = 1.0 (self loop), cnt = 0 ----------------
__global__ void k_init(float* __restrict__ deg, int* __restrict__ cnt) {
    int i = blockIdx.x * 256 + threadIdx.x;
    if (i < N_CNT) { deg[i] = 1.0f; cnt[i] = 0; }
}

// ---------------- edge MLP + degree/count accumulation ----------------
__global__ void k_edge_mlp(const int* __restrict__ src, const int* __restrict__ dst,
                           const float* __restrict__ attr,
                           const float* __restrict__ W1, const float* __restrict__ b1,
                           const float* __restrict__ W2, const float* __restrict__ b2,
                           float* __restrict__ wbuf, float* __restrict__ deg,
                           int* __restrict__ cnt) {
    __shared__ float sW1[ATTR_D * H_DIM];
    __shared__ float sb1[H_DIM];
    __shared__ float sW2[H_DIM];
    __shared__ float sb2;
    int t = threadIdx.x;
    sW1[t] = W1[t];                      // blockDim==256==ATTR_D*H_DIM
    if (t < H_DIM) { sb1[t] = b1[t]; sW2[t] = W2[t]; }
    if (t == 0) sb2 = b2[0];
    __syncthreads();
    int e = blockIdx.x * 256 + t;
    if (e >= E_CNT) return;
    const float4* a4 = (const float4*)attr;     // fp32 rows are 32B: two float4
    float4 r0 = a4[e * 2 + 0];
    float4 r1 = a4[e * 2 + 1];
    float a[8] = {r0.x, r0.y, r0.z, r0.w, r1.x, r1.y, r1.z, r1.w};
    float z = sb2;
    #pragma unroll
    for (int h = 0; h < H_DIM; ++h) {
        float acc = sb1[h];
        #pragma unroll
        for (int k = 0; k < 8; ++k) acc = fmaf(a[k], sW1[k * H_DIM + h], acc);
        acc = fmaxf(acc, 0.0f);
        z = fmaf(acc, sW2[h], z);
    }
    float w = 1.0f / (1.0f + __expf(-z));
    w = fmaxf(w, 1e-6f);
    wbuf[e] = w;
    int s = src[e], d = U_CNT + dst[e];
    atomicAdd(&deg[s], w);
    atomicAdd(&deg[d], w);
    atomicAdd(&cnt[s], 1);
    atomicAdd(&cnt[d], 1);
}

// ---------------- exclusive scan of cnt -> offs (3 kernels) ----------------
__global__ void k_scan1(const int* __restrict__ cnt, int* __restrict__ incl,
                        int* __restrict__ bsums) {
    __shared__ int s[256];
    int t = threadIdx.x;
    int i = blockIdx.x * 256 + t;
    int v = (i < N_CNT) ? cnt[i] : 0;
    s[t] = v;
    __syncthreads();
    #pragma unroll
    for (int off = 1; off < 256; off <<= 1) {
        int x = (t >= off) ? s[t - off] : 0;
        __syncthreads();
        s[t] += x;
        __syncthreads();
    }
    if (i < N_CNT) incl[i] = s[t];
    if (t == 255) bsums[blockIdx.x] = s[255];
}

__global__ void k_scan2(const int* __restrict__ bsums, int* __restrict__ bbase, int nb) {
    __shared__ int s[256];
    __shared__ int carry_s;
    int t = threadIdx.x;
    if (t == 0) carry_s = 0;
    __syncthreads();
    for (int start = 0; start < nb; start += 256) {
        int i = start + t;
        int v = (i < nb) ? bsums[i] : 0;
        s[t] = v;
        __syncthreads();
        #pragma unroll
        for (int off = 1; off < 256; off <<= 1) {
            int x = (t >= off) ? s[t - off] : 0;
            __syncthreads();
            s[t] += x;
            __syncthreads();
        }
        int carry = carry_s;
        if (i < nb) bbase[i] = carry + s[t] - v;  // exclusive
        __syncthreads();
        if (t == 255) carry_s += s[255];
        __syncthreads();
    }
}

__global__ void k_scan3(const int* __restrict__ incl, const int* __restrict__ cnt,
                        const int* __restrict__ bbase, const float* __restrict__ deg,
                        int* __restrict__ offs, int* __restrict__ cursor,
                        float* __restrict__ dis) {
    int i = blockIdx.x * 256 + threadIdx.x;
    if (i < N_CNT) {
        int v = bbase[blockIdx.x] + incl[i] - cnt[i];
        offs[i] = v;
        cursor[i] = v;
        dis[i] = rsqrtf(deg[i]);   // deg >= 1 always (self loop)
    }
    if (i == 0) offs[N_CNT] = 2 * E_CNT;
}

// ---------------- scatter edges into CSR (both directions) ----------------
__global__ void k_scatter(const int* __restrict__ src, const int* __restrict__ dst,
                          const float* __restrict__ wbuf, const float* __restrict__ dis,
                          int* __restrict__ cursor, int2* __restrict__ csr) {
    int e = blockIdx.x * 256 + threadIdx.x;
    if (e >= E_CNT) return;
    float w = wbuf[e];
    int s = src[e], d = U_CNT + dst[e];
    float dsrc = dis[s], ddst = dis[d];
    int pA = atomicAdd(&cursor[d], 1);
    csr[pA] = make_int2(s, __float_as_int(dsrc * w));   // col=d, row=s
    int pB = atomicAdd(&cursor[s], 1);
    csr[pB] = make_int2(d, __float_as_int(ddst * w));   // col=s, row=d
}

// ---------------- initial features: users (l2norm), wave per row ----------------
__global__ void k_users(const float* __restrict__ user_w, float* __restrict__ x0,
                        float* __restrict__ acc) {
    int lane = threadIdx.x & 63;
    int wv = (blockIdx.x * blockDim.x + threadIdx.x) >> 6;
    int nw = (gridDim.x * blockDim.x) >> 6;
    for (int r = wv; r < U_CNT; r += nw) {
        int idx = r * 64 + lane;
        float v = user_w[idx];
        float ss = v * v;
        #pragma unroll
        for (int m = 32; m >= 1; m >>= 1) ss += __shfl_xor(ss, m, 64);
        float inv = 1.0f / fmaxf(sqrtf(ss), 1e-12f);
        float o = v * inv;
        x0[idx] = o;
        acc[idx] = o;
    }
}

// ---------------- initial features: items (meta + projection + l2norm) ----------------
__global__ void __launch_bounds__(256, 1)
k_items(const float* __restrict__ audio, const float* __restrict__ art,
        const float* __restrict__ alb, const int* __restrict__ aid,
        const int* __restrict__ alid, const float* __restrict__ Wp,
        const float* __restrict__ bp, float* __restrict__ x0item,
        float* __restrict__ accitem) {
    int lane = threadIdx.x & 63;
    // lane d holds column d of Wp [128 x 64] in registers (branch-free -> SROA)
    float wreg[128];
    #pragma unroll
    for (int k = 0; k < 128; ++k) wreg[k] = Wp[k * 64 + lane];
    float bias = bp[lane];
    int wv = (blockIdx.x * blockDim.x + threadIdx.x) >> 6;
    int nw = (gridDim.x * blockDim.x) >> 6;
    for (int i = wv; i < I_CNT; i += nw) {
        float vlow = audio[i * 64 + lane];   // AUDIO_SCALE=1
        int a_ = aid[i], al_ = alid[i];
        float vhigh = art[a_ * 64 + lane] + alb[al_ * 64 + lane];  // META_SCALE=1
        float a0 = bias, a1 = 0.f, a2 = 0.f, a3 = 0.f;
        #pragma unroll
        for (int k = 0; k < 64; k += 4) {
            a0 = fmaf(__shfl(vlow, k + 0, 64), wreg[k + 0], a0);
            a1 = fmaf(__shfl(vlow, k + 1, 64), wreg[k + 1], a1);
            a2 = fmaf(__shfl(vlow, k + 2, 64), wreg[k + 2], a2);
            a3 = fmaf(__shfl(vlow, k + 3, 64), wreg[k + 3], a3);
        }
        #pragma unroll
        for (int k = 0; k < 64; k += 4) {
            a0 = fmaf(__shfl(vhigh, k + 0, 64), wreg[64 + k + 0], a0);
            a1 = fmaf(__shfl(vhigh, k + 1, 64), wreg[64 + k + 1], a1);
            a2 = fmaf(__shfl(vhigh, k + 2, 64), wreg[64 + k + 2], a2);
            a3 = fmaf(__shfl(vhigh, k + 3, 64), wreg[64 + k + 3], a3);
        }
        float o = (a0 + a1) + (a2 + a3);
        float ss = o * o;
        #pragma unroll
        for (int m = 32; m >= 1; m >>= 1) ss += __shfl_xor(ss, m, 64);
        o = o / fmaxf(sqrtf(ss), 1e-12f);
        int idx = i * 64 + lane;
        x0item[idx] = o;
        accitem[idx] = o;
    }
}

// ---------------- one LGConv propagation round (gather CSR) ----------------
__global__ void k_prop(const int* __restrict__ offs, const int2* __restrict__ csr,
                       const float* __restrict__ dis,
                       const float* __restrict__ xin, float* __restrict__ xout,
                       float* __restrict__ acc) {
    int lane = threadIdx.x & 63;
    int c = (blockIdx.x * 256 + threadIdx.x) >> 6;   // wave per node
    if (c >= N_CNT) return;
    int e = offs[c], end = offs[c + 1];
    float dc = dis[c];
    float s0 = 0.f, s1 = 0.f, s2 = 0.f, s3 = 0.f;
    for (; e + 3 < end; e += 4) {
        int2 e0 = csr[e], e1 = csr[e + 1], e2 = csr[e + 2], e3 = csr[e + 3];
        float x0v = xin[e0.x * 64 + lane];
        float x1v = xin[e1.x * 64 + lane];
        float x2v = xin[e2.x * 64 + lane];
        float x3v = xin[e3.x * 64 + lane];
        s0 = fmaf(__int_as_float(e0.y), x0v, s0);
        s1 = fmaf(__int_as_float(e1.y), x1v, s1);
        s2 = fmaf(__int_as_float(e2.y), x2v, s2);
        s3 = fmaf(__int_as_float(e3.y), x3v, s3);
    }
    for (; e < end; ++e) {
        int2 ee = csr[e];
        s0 = fmaf(__int_as_float(ee.y), xin[ee.x * 64 + lane], s0);
    }
    float sum = (s0 + s1) + (s2 + s3);
    int idx = c * 64 + lane;
    float selfv = xin[idx];
    float res = fmaf(dc, sum, selfv * dc * dc);     // self loop: dis^2 * x
    xout[idx] = res;
    acc[idx] += res;
}

// ---------------- epilogue: l2norm(acc/4), wave per node ----------------
__global__ void k_final(const float* __restrict__ acc, float* __restrict__ out) {
    int lane = threadIdx.x & 63;
    int c = (blockIdx.x * 256 + threadIdx.x) >> 6;
    if (c >= N_CNT) return;
    int idx = c * 64 + lane;
    float v = acc[idx];
    float ss = v * v;
    #pragma unroll
    for (int m = 32; m >= 1; m >>= 1) ss += __shfl_xor(ss, m, 64);
    float n = sqrtf(ss) * 0.25f;
    out[idx] = (v * 0.25f) / fmaxf(n, 1e-12f);
}

extern "C" void kernel_launch(void* const* d_in, const int* in_sizes, int n_in,
                              void* d_out, int out_size, void* d_ws, size_t ws_size,
                              hipStream_t stream) {
    const int*   edge_src   = (const int*)  d_in[0];
    const int*   edge_dst   = (const int*)  d_in[1];
    const float* edge_attr  = (const float*)d_in[2];
    const float* user_w     = (const float*)d_in[3];
    const float* artist_w   = (const float*)d_in[4];
    const float* album_w    = (const float*)d_in[5];
    const float* item_audio = (const float*)d_in[6];
    const int*   artist_ids = (const int*)  d_in[7];
    const int*   album_ids  = (const int*)  d_in[8];
    const float* Wp         = (const float*)d_in[9];
    const float* bp         = (const float*)d_in[10];
    const float* W1         = (const float*)d_in[11];
    const float* b1         = (const float*)d_in[12];
    const float* W2         = (const float*)d_in[13];
    const float* b2         = (const float*)d_in[14];

    // workspace carve (256B-aligned): ~181 MB (round-2 proven footprint)
    char* p = (char*)d_ws;
    auto carve = [&](size_t bytes) -> void* {
        void* q = (void*)p;
        p += (bytes + 255) & ~(size_t)255;
        return q;
    };
    float* deg    = (float*)carve((size_t)N_CNT * 4);
    float* dis    = (float*)carve((size_t)N_CNT * 4);
    float* wbuf   = (float*)carve((size_t)E_CNT * 4);
    int*   cnt    = (int*)  carve((size_t)N_CNT * 4);
    int*   offs   = (int*)  carve((size_t)(N_CNT + 1) * 4);
    int*   cursor = (int*)  carve((size_t)N_CNT * 4);
    int*   incl   = (int*)  carve((size_t)N_CNT * 4);
    int*   bsums  = (int*)  carve((size_t)NB_SCAN * 4);
    int*   bbase  = (int*)  carve((size_t)NB_SCAN * 4);
    int2*  csr    = (int2*) carve((size_t)2 * E_CNT * 8);
    float* xa     = (float*)carve((size_t)N_CNT * 64 * 4);
    float* acc    = (float*)carve((size_t)N_CNT * 64 * 4);
    float* xb     = (float*)d_out;   // proven safe in round 2: d_out as ping-pong
    (void)ws_size; (void)in_sizes; (void)n_in; (void)out_size;

    k_init   <<<(N_CNT + 255) / 256, 256, 0, stream>>>(deg, cnt);
    k_edge_mlp<<<(E_CNT + 255) / 256, 256, 0, stream>>>(edge_src, edge_dst, edge_attr,
                                                        W1, b1, W2, b2, wbuf, deg, cnt);
    k_scan1  <<<NB_SCAN, 256, 0, stream>>>(cnt, incl, bsums);
    k_scan2  <<<1, 256, 0, stream>>>(bsums, bbase, NB_SCAN);
    k_scan3  <<<NB_SCAN, 256, 0, stream>>>(incl, cnt, bbase, deg, offs, cursor, dis);
    k_scatter<<<(E_CNT + 255) / 256, 256, 0, stream>>>(edge_src, edge_dst, wbuf, dis,
                                                       cursor, csr);
    k_users  <<<1024, 256, 0, stream>>>(user_w, xa, acc);
    k_items  <<<1024, 256, 0, stream>>>(item_audio, artist_w, album_w, artist_ids,
                                        album_ids, Wp, bp,
                                        xa + (size_t)U_CNT * 64,
                                        acc + (size_t)U_CNT * 64);
    // 3 LGConv rounds: xa -> xb(d_out) -> xa -> xb, accumulating into acc
    k_prop   <<<N_CNT / 4, 256, 0, stream>>>(offs, csr, dis, xa, xb, acc);
    k_prop   <<<N_CNT / 4, 256, 0, stream>>>(offs, csr, dis, xb, xa, acc);
    k_prop   <<<N_CNT / 4, 256, 0, stream>>>(offs, csr, dis, xa, xb, acc);
    k_final  <<<N_CNT / 4, 256, 0, stream>>>(acc, (float*)d_out);
}

// Round 6
// 1105.504 us; speedup vs baseline: 1.7814x; 1.0418x over previous
//
#include <hip/hip_runtime.h>
#include <hip/hip_bf16.h>

#define U_CNT 200000
#define I_CNT 100000
#define N_CNT 300000
#define E_CNT 1000000
#define ATTR_D 8
#define H_DIM 32
#define NB_SCAN ((N_CNT + 255) / 256)

// NOTE (rounds 1-4): all float inputs and the output are FLOAT32. absmax floor
// 1.95e-3 == bf16 rounding of the *reference*; threshold 1.26e-2.
// NOTE (round 5): k_edge_mlp was atomic-bound (4M atomics x 32B = 128MB
// WRITE_SIZE). Round 6 removes the 2M deg-float atomics: deg is computed
// post-scatter by segment sum (k_deg), dis[row] folded in by k_rescale.

// ---------------- edge MLP + count histogram (2M int atomics only) ----------------
__global__ void k_edge_mlp(const int* __restrict__ src, const int* __restrict__ dst,
                           const float* __restrict__ attr,
                           const float* __restrict__ W1, const float* __restrict__ b1,
                           const float* __restrict__ W2, const float* __restrict__ b2,
                           float* __restrict__ wbuf, int* __restrict__ cnt) {
    __shared__ float sW1[ATTR_D * H_DIM];
    __shared__ float sb1[H_DIM];
    __shared__ float sW2[H_DIM];
    __shared__ float sb2;
    int t = threadIdx.x;
    sW1[t] = W1[t];                      // blockDim==256==ATTR_D*H_DIM
    if (t < H_DIM) { sb1[t] = b1[t]; sW2[t] = W2[t]; }
    if (t == 0) sb2 = b2[0];
    __syncthreads();
    int e = blockIdx.x * 256 + t;
    if (e >= E_CNT) return;
    const float4* a4 = (const float4*)attr;     // 32B/row: two float4
    float4 r0 = a4[e * 2 + 0];
    float4 r1 = a4[e * 2 + 1];
    float a[8] = {r0.x, r0.y, r0.z, r0.w, r1.x, r1.y, r1.z, r1.w};
    float z = sb2;
    #pragma unroll
    for (int h = 0; h < H_DIM; ++h) {
        float acc = sb1[h];
        #pragma unroll
        for (int k = 0; k < 8; ++k) acc = fmaf(a[k], sW1[k * H_DIM + h], acc);
        acc = fmaxf(acc, 0.0f);
        z = fmaf(acc, sW2[h], z);
    }
    float w = 1.0f / (1.0f + __expf(-z));
    w = fmaxf(w, 1e-6f);
    wbuf[e] = w;
    int s = src[e], d = U_CNT + dst[e];
    atomicAdd(&cnt[s], 1);
    atomicAdd(&cnt[d], 1);
}

// ---------------- exclusive scan of cnt -> offs (3 kernels) ----------------
__global__ void k_scan1(const int* __restrict__ cnt, int* __restrict__ incl,
                        int* __restrict__ bsums) {
    __shared__ int s[256];
    int t = threadIdx.x;
    int i = blockIdx.x * 256 + t;
    int v = (i < N_CNT) ? cnt[i] : 0;
    s[t] = v;
    __syncthreads();
    #pragma unroll
    for (int off = 1; off < 256; off <<= 1) {
        int x = (t >= off) ? s[t - off] : 0;
        __syncthreads();
        s[t] += x;
        __syncthreads();
    }
    if (i < N_CNT) incl[i] = s[t];
    if (t == 255) bsums[blockIdx.x] = s[255];
}

__global__ void k_scan2(const int* __restrict__ bsums, int* __restrict__ bbase, int nb) {
    __shared__ int s[256];
    __shared__ int carry_s;
    int t = threadIdx.x;
    if (t == 0) carry_s = 0;
    __syncthreads();
    for (int start = 0; start < nb; start += 256) {
        int i = start + t;
        int v = (i < nb) ? bsums[i] : 0;
        s[t] = v;
        __syncthreads();
        #pragma unroll
        for (int off = 1; off < 256; off <<= 1) {
            int x = (t >= off) ? s[t - off] : 0;
            __syncthreads();
            s[t] += x;
            __syncthreads();
        }
        int carry = carry_s;
        if (i < nb) bbase[i] = carry + s[t] - v;  // exclusive
        __syncthreads();
        if (t == 255) carry_s += s[255];
        __syncthreads();
    }
}

__global__ void k_scan3(const int* __restrict__ incl, const int* __restrict__ cnt,
                        const int* __restrict__ bbase,
                        int* __restrict__ offs, int* __restrict__ cursor) {
    int i = blockIdx.x * 256 + threadIdx.x;
    if (i < N_CNT) {
        int v = bbase[blockIdx.x] + incl[i] - cnt[i];
        offs[i] = v;
        cursor[i] = v;
    }
    if (i == 0) offs[N_CNT] = 2 * E_CNT;
}

// ---------------- scatter edges into CSR (store raw w; no dis yet) ----------------
__global__ void k_scatter(const int* __restrict__ src, const int* __restrict__ dst,
                          const float* __restrict__ wbuf,
                          int* __restrict__ cursor, int2* __restrict__ csr) {
    int e = blockIdx.x * 256 + threadIdx.x;
    if (e >= E_CNT) return;
    float w = wbuf[e];
    int s = src[e], d = U_CNT + dst[e];
    int pA = atomicAdd(&cursor[d], 1);
    csr[pA] = make_int2(s, __float_as_int(w));   // col=d, row=s
    int pB = atomicAdd(&cursor[s], 1);
    csr[pB] = make_int2(d, __float_as_int(w));   // col=s, row=d
}

// ---------------- deg via segment sum (no atomics), dis = rsqrt(1+sum) ----------------
__global__ void k_deg(const int* __restrict__ offs, const int2* __restrict__ csr,
                      float* __restrict__ dis) {
    int i = blockIdx.x * 256 + threadIdx.x;
    if (i >= N_CNT) return;
    int b = offs[i], e = offs[i + 1];
    float s = 1.0f;                      // self loop weight
    for (int k = b; k < e; ++k) s += __int_as_float(csr[k].y);
    dis[i] = rsqrtf(s);                  // s >= 1 always
}

// ---------------- fold dis[row] into stored weights ----------------
__global__ void k_rescale(const float* __restrict__ dis, int2* __restrict__ csr) {
    int i = blockIdx.x * 256 + threadIdx.x;
    if (i >= 2 * E_CNT) return;
    int2 v = csr[i];
    csr[i] = make_int2(v.x, __float_as_int(__int_as_float(v.y) * dis[v.x]));
}

// ---------------- initial features: users (l2norm), wave per row ----------------
__global__ void k_users(const float* __restrict__ user_w, float* __restrict__ x0,
                        float* __restrict__ acc, int use_acc) {
    int lane = threadIdx.x & 63;
    int wv = (blockIdx.x * blockDim.x + threadIdx.x) >> 6;
    int nw = (gridDim.x * blockDim.x) >> 6;
    for (int r = wv; r < U_CNT; r += nw) {
        int idx = r * 64 + lane;
        float v = user_w[idx];
        float ss = v * v;
        #pragma unroll
        for (int m = 32; m >= 1; m >>= 1) ss += __shfl_xor(ss, m, 64);
        float inv = 1.0f / fmaxf(sqrtf(ss), 1e-12f);
        float o = v * inv;
        x0[idx] = o;
        if (use_acc) acc[idx] = o;
    }
}

// ---------------- initial features: items (meta + projection + l2norm) ----------------
__global__ void __launch_bounds__(256, 1)
k_items(const float* __restrict__ audio, const float* __restrict__ art,
        const float* __restrict__ alb, const int* __restrict__ aid,
        const int* __restrict__ alid, const float* __restrict__ Wp,
        const float* __restrict__ bp, float* __restrict__ x0item,
        float* __restrict__ accitem, int use_acc) {
    int lane = threadIdx.x & 63;
    float wreg[128];                     // lane d holds column d of Wp [128x64]
    #pragma unroll
    for (int k = 0; k < 128; ++k) wreg[k] = Wp[k * 64 + lane];
    float bias = bp[lane];
    int wv = (blockIdx.x * blockDim.x + threadIdx.x) >> 6;
    int nw = (gridDim.x * blockDim.x) >> 6;
    for (int i = wv; i < I_CNT; i += nw) {
        float vlow = audio[i * 64 + lane];   // AUDIO_SCALE=1
        int a_ = aid[i], al_ = alid[i];
        float vhigh = art[a_ * 64 + lane] + alb[al_ * 64 + lane];  // META_SCALE=1
        float a0 = bias, a1 = 0.f, a2 = 0.f, a3 = 0.f;
        #pragma unroll
        for (int k = 0; k < 64; k += 4) {
            a0 = fmaf(__shfl(vlow, k + 0, 64), wreg[k + 0], a0);
            a1 = fmaf(__shfl(vlow, k + 1, 64), wreg[k + 1], a1);
            a2 = fmaf(__shfl(vlow, k + 2, 64), wreg[k + 2], a2);
            a3 = fmaf(__shfl(vlow, k + 3, 64), wreg[k + 3], a3);
        }
        #pragma unroll
        for (int k = 0; k < 64; k += 4) {
            a0 = fmaf(__shfl(vhigh, k + 0, 64), wreg[64 + k + 0], a0);
            a1 = fmaf(__shfl(vhigh, k + 1, 64), wreg[64 + k + 1], a1);
            a2 = fmaf(__shfl(vhigh, k + 2, 64), wreg[64 + k + 2], a2);
            a3 = fmaf(__shfl(vhigh, k + 3, 64), wreg[64 + k + 3], a3);
        }
        float o = (a0 + a1) + (a2 + a3);
        float ss = o * o;
        #pragma unroll
        for (int m = 32; m >= 1; m >>= 1) ss += __shfl_xor(ss, m, 64);
        o = o / fmaxf(sqrtf(ss), 1e-12f);
        int idx = i * 64 + lane;
        x0item[idx] = o;
        if (use_acc) accitem[idx] = o;
    }
}

// ---------------- one LGConv propagation round (gather CSR) ----------------
__global__ void k_prop(const int* __restrict__ offs, const int2* __restrict__ csr,
                       const float* __restrict__ dis,
                       const float* __restrict__ xin, float* __restrict__ xout,
                       float* __restrict__ acc, int use_acc) {
    int lane = threadIdx.x & 63;
    int c = (blockIdx.x * 256 + threadIdx.x) >> 6;   // wave per node
    if (c >= N_CNT) return;
    int e = offs[c], end = offs[c + 1];
    float dc = dis[c];
    float s0 = 0.f, s1 = 0.f, s2 = 0.f, s3 = 0.f;
    for (; e + 3 < end; e += 4) {
        int2 e0 = csr[e], e1 = csr[e + 1], e2 = csr[e + 2], e3 = csr[e + 3];
        float x0v = xin[e0.x * 64 + lane];
        float x1v = xin[e1.x * 64 + lane];
        float x2v = xin[e2.x * 64 + lane];
        float x3v = xin[e3.x * 64 + lane];
        s0 = fmaf(__int_as_float(e0.y), x0v, s0);
        s1 = fmaf(__int_as_float(e1.y), x1v, s1);
        s2 = fmaf(__int_as_float(e2.y), x2v, s2);
        s3 = fmaf(__int_as_float(e3.y), x3v, s3);
    }
    for (; e < end; ++e) {
        int2 ee = csr[e];
        s0 = fmaf(__int_as_float(ee.y), xin[ee.x * 64 + lane], s0);
    }
    float sum = (s0 + s1) + (s2 + s3);
    int idx = c * 64 + lane;
    float selfv = xin[idx];
    float res = fmaf(dc, sum, selfv * dc * dc);     // self loop: dis^2 * x
    xout[idx] = res;
    if (use_acc) acc[idx] += res;
}

// ---------------- epilogue A: l2norm(acc/4) ----------------
__global__ void k_final_acc(const float* __restrict__ acc, float* __restrict__ out) {
    int lane = threadIdx.x & 63;
    int c = (blockIdx.x * 256 + threadIdx.x) >> 6;
    if (c >= N_CNT) return;
    int idx = c * 64 + lane;
    float v = acc[idx];
    float ss = v * v;
    #pragma unroll
    for (int m = 32; m >= 1; m >>= 1) ss += __shfl_xor(ss, m, 64);
    float n = sqrtf(ss) * 0.25f;
    out[idx] = (v * 0.25f) / fmaxf(n, 1e-12f);
}

// ---------------- epilogue B: l2norm((x0+x1+x2+x3)/4), x3 lives in out ----------------
__global__ void k_final_sum(const float* __restrict__ x0, const float* __restrict__ x1,
                            const float* __restrict__ x2, float* __restrict__ out) {
    int lane = threadIdx.x & 63;
    int c = (blockIdx.x * 256 + threadIdx.x) >> 6;
    if (c >= N_CNT) return;
    int idx = c * 64 + lane;
    float v = x0[idx] + x1[idx] + x2[idx] + out[idx];
    float ss = v * v;
    #pragma unroll
    for (int m = 32; m >= 1; m >>= 1) ss += __shfl_xor(ss, m, 64);
    float n = sqrtf(ss) * 0.25f;
    out[idx] = (v * 0.25f) / fmaxf(n, 1e-12f);
}

extern "C" void kernel_launch(void* const* d_in, const int* in_sizes, int n_in,
                              void* d_out, int out_size, void* d_ws, size_t ws_size,
                              hipStream_t stream) {
    const int*   edge_src   = (const int*)  d_in[0];
    const int*   edge_dst   = (const int*)  d_in[1];
    const float* edge_attr  = (const float*)d_in[2];
    const float* user_w     = (const float*)d_in[3];
    const float* artist_w   = (const float*)d_in[4];
    const float* album_w    = (const float*)d_in[5];
    const float* item_audio = (const float*)d_in[6];
    const int*   artist_ids = (const int*)  d_in[7];
    const int*   album_ids  = (const int*)  d_in[8];
    const float* Wp         = (const float*)d_in[9];
    const float* bp         = (const float*)d_in[10];
    const float* W1         = (const float*)d_in[11];
    const float* b1         = (const float*)d_in[12];
    const float* W2         = (const float*)d_in[13];
    const float* b2         = (const float*)d_in[14];

    char* p = (char*)d_ws;
    auto carve = [&](size_t bytes) -> void* {
        void* q = (void*)p;
        p += (bytes + 255) & ~(size_t)255;
        return q;
    };
    // common carve (~25.3 MB)
    float* dis    = (float*)carve((size_t)N_CNT * 4);
    float* wbuf   = (float*)carve((size_t)E_CNT * 4);
    int*   cnt    = (int*)  carve((size_t)N_CNT * 4);
    int*   offs   = (int*)  carve((size_t)(N_CNT + 1) * 4);
    int*   cursor = (int*)  carve((size_t)N_CNT * 4);
    int*   incl   = (int*)  carve((size_t)N_CNT * 4);
    int*   bsums  = (int*)  carve((size_t)NB_SCAN * 4);
    int*   bbase  = (int*)  carve((size_t)NB_SCAN * 4);
    int2*  csr    = (int2*) carve((size_t)2 * E_CNT * 8);
    const size_t XB = (size_t)N_CNT * 64 * 4;      // 76.8 MB per x buffer
    size_t used = (size_t)(p - (char*)d_ws);
    // Path B (no acc RMW) needs x0,x1,x2 in ws; x3 = d_out.
    int no_acc = (ws_size >= used + 3 * XB + (size_t)4096) ? 1 : 0;
    float *x0, *x1, *x2, *acc = nullptr;
    if (no_acc) {
        x0 = (float*)carve(XB);
        x1 = (float*)carve(XB);
        x2 = (float*)carve(XB);
    } else {
        x0 = (float*)carve(XB);        // xa
        acc = (float*)carve(XB);
        x1 = (float*)d_out;            // ping-pong via d_out (proven round 2/5)
        x2 = x0;
    }
    (void)in_sizes; (void)n_in; (void)out_size;

    hipMemsetAsync(cnt, 0, (size_t)N_CNT * 4, stream);
    k_edge_mlp<<<(E_CNT + 255) / 256, 256, 0, stream>>>(edge_src, edge_dst, edge_attr,
                                                        W1, b1, W2, b2, wbuf, cnt);
    k_scan1  <<<NB_SCAN, 256, 0, stream>>>(cnt, incl, bsums);
    k_scan2  <<<1, 256, 0, stream>>>(bsums, bbase, NB_SCAN);
    k_scan3  <<<NB_SCAN, 256, 0, stream>>>(incl, cnt, bbase, offs, cursor);
    k_scatter<<<(E_CNT + 255) / 256, 256, 0, stream>>>(edge_src, edge_dst, wbuf,
                                                       cursor, csr);
    k_deg    <<<NB_SCAN, 256, 0, stream>>>(offs, csr, dis);
    k_rescale<<<(2 * E_CNT + 255) / 256, 256, 0, stream>>>(dis, csr);
    k_users  <<<1024, 256, 0, stream>>>(user_w, x0, acc, no_acc ? 0 : 1);
    k_items  <<<1024, 256, 0, stream>>>(item_audio, artist_w, album_w, artist_ids,
                                        album_ids, Wp, bp,
                                        x0 + (size_t)U_CNT * 64,
                                        no_acc ? nullptr : acc + (size_t)U_CNT * 64,
                                        no_acc ? 0 : 1);
    if (no_acc) {
        float* x3 = (float*)d_out;
        k_prop<<<N_CNT / 4, 256, 0, stream>>>(offs, csr, dis, x0, x1, nullptr, 0);
        k_prop<<<N_CNT / 4, 256, 0, stream>>>(offs, csr, dis, x1, x2, nullptr, 0);
        k_prop<<<N_CNT / 4, 256, 0, stream>>>(offs, csr, dis, x2, x3, nullptr, 0);
        k_final_sum<<<N_CNT / 4, 256, 0, stream>>>(x0, x1, x2, (float*)d_out);
    } else {
        // x0 -> x1(d_out) -> x0 -> x1, accumulating into acc
        k_prop<<<N_CNT / 4, 256, 0, stream>>>(offs, csr, dis, x0, x1, acc, 1);
        k_prop<<<N_CNT / 4, 256, 0, stream>>>(offs, csr, dis, x1, x0, acc, 1);
        k_prop<<<N_CNT / 4, 256, 0, stream>>>(offs, csr, dis, x0, x1, acc, 1);
        k_final_acc<<<N_CNT / 4, 256, 0, stream>>>(acc, (float*)d_out);
    }
}